// Round 2
// baseline (171.338 us; speedup 1.0000x reference)
//
#include <hip/hip_runtime.h>

#define WIDTH 2048
#define N_LAYERS 24
#define NUM_NEURONS ((N_LAYERS + 1) * WIDTH)
#define NB 256           // 1 block/CU
#define NT 1024          // 16 waves
#define RPB 8            // rows per block
#define HC 1024          // half-row cols owned by one wave
#define LAYER_ELEMS ((size_t)WIDTH * WIDTH)

typedef unsigned long long u64;
#define WS_NEEDED (NUM_NEURONS * sizeof(u64))
// epoch path: vals[NUM_NEURONS] + ctrl block {magic, done, rsvd...}
#define WS_EPOCH_NEEDED (WS_NEEDED + 64)
#define MAGIC_V 0x7E57C0DE5EED0001ull
#define SB0() __builtin_amdgcn_sched_barrier(0)

// ---- dataflow primitives: (tag<<32 | f32bits) in one 8B agent atomic ----
// tag must equal current launch epoch E; stale launches carry E-1.
__device__ __forceinline__ float resolve(const u64* p, u64 v, unsigned E) {
    while ((unsigned)(v >> 32) != E) {
        __builtin_amdgcn_s_sleep(1);
        v = __hip_atomic_load(p, __ATOMIC_RELAXED, __HIP_MEMORY_SCOPE_AGENT);
    }
    union { unsigned u; float f; } c; c.u = (unsigned)v; return c.f;
}
__device__ __forceinline__ void publish(u64* p, float f, unsigned E) {
    union { float f; unsigned u; } c; c.f = f;
    __hip_atomic_store(p, ((u64)E << 32) | (u64)c.u, __ATOMIC_RELAXED,
                       __HIP_MEMORY_SCOPE_AGENT);
}

// prep: idempotent workspace init. Early-outs after first launch (~2us);
// zeroes vals only when the ws is virgin/poisoned (magic mismatch).
__global__ __launch_bounds__(256) void prep(u64* __restrict__ vals) {
    u64* ctrl = vals + NUM_NEURONS;   // [0]=magic, [1]=done
    if (__hip_atomic_load(&ctrl[0], __ATOMIC_RELAXED,
                          __HIP_MEMORY_SCOPE_AGENT) == MAGIC_V)
        return;
    int i = blockIdx.x * blockDim.x + threadIdx.x;
    int stride = gridDim.x * blockDim.x;
    for (int e = i; e < NUM_NEURONS; e += stride)
        __hip_atomic_store(&vals[e], 0ull, __ATOMIC_RELAXED,
                           __HIP_MEMORY_SCOPE_AGENT);
    if (i == 0) {
        __hip_atomic_store(&ctrl[1], 0ull, __ATOMIC_RELAXED,
                           __HIP_MEMORY_SCOPE_AGENT);
        __hip_atomic_store(&ctrl[0], MAGIC_V, __ATOMIC_RELAXED,
                           __HIP_MEMORY_SCOPE_AGENT);
    }
}

// One layer of the register-double-buffered pipeline.
// wc/mc: THIS layer's slice (issued one layer ago; forced complete by the
// counted wait at resolve -- polls are OLDER than wn/mn's loads, so the
// compiler's vmcnt at the poll check lets wn/mn stay in flight: no drain).
// wn/mn: NEXT layer's slice, issued here.
__device__ __forceinline__ void layer_body(
    int l, unsigned E,
    const float* __restrict__ W, const float* __restrict__ M,
    const float* __restrict__ B, const int* __restrict__ IDX,
    u64* __restrict__ vals, float* __restrict__ out,
    float4 (&wc)[4], float4 (&mc)[4],
    float4 (&wn)[4], float4 (&mn)[4],
    int2& I_cur, int& myidx, float& bias,
    float* v_lds, float* wsum,
    int t, int w, int lane, int h, int bid, size_t slice_off)
{
    const int ln = (l + 1 < N_LAYERS) ? l + 1 : 0;   // scalar-prefetch wrap

    // ---- P2: polls FIRST (oldest vmem ops), then next-layer scalars ----
    u64 pa = __hip_atomic_load(vals + I_cur.x, __ATOMIC_RELAXED,
                               __HIP_MEMORY_SCOPE_AGENT);
    u64 pb = __hip_atomic_load(vals + I_cur.y, __ATOMIC_RELAXED,
                               __HIP_MEMORY_SCOPE_AGENT);
    int2  I_next    = ((const int2*)(IDX + ln * WIDTH))[t];
    int   myidx_nxt = (t < RPB) ? IDX[ln * WIDTH + bid * RPB + t] : 0;
    float bias_nxt  = (t < RPB) ? B[ln * WIDTH + bid * RPB + t]   : 0.0f;
    SB0();

    // ---- P3: issue next-layer slice into registers (8 x dwordx4) ----
    if (l + 1 < N_LAYERS) {
        const float* ws = W + (size_t)(l + 1) * LAYER_ELEMS + slice_off;
        const float* ms = M + (size_t)(l + 1) * LAYER_ELEMS + slice_off;
#pragma unroll
        for (int i = 0; i < 4; ++i) {
            wn[i] = *(const float4*)(ws + i * 256);
            mn[i] = *(const float4*)(ms + i * 256);
        }
    }
    SB0();

    // ---- P4: resolve (fast path: counted vmcnt -> wc/mc complete,
    //      wn/mn remain in flight), fill v ----
    float a = resolve(vals + I_cur.x, pa, E);
    float b = resolve(vals + I_cur.y, pb, E);
    v_lds[2 * t]     = a;
    v_lds[2 * t + 1] = b;
    asm volatile("s_waitcnt lgkmcnt(0)" ::: "memory");
    SB0();
    __builtin_amdgcn_s_barrier();        // #1: v ready

    // ---- P5: dot from registers x shared v (R15-exact FP order) ----
    float acc = 0.0f;
    {
        const float4* Vr = (const float4*)v_lds + h * (HC / 4);
#pragma unroll
        for (int i = 0; i < 4; ++i) {
            float4 vv = Vr[lane + i * 64];
            acc += wc[i].x * mc[i].x * vv.x;
            acc += wc[i].y * mc[i].y * vv.y;
            acc += wc[i].z * mc[i].z * vv.z;
            acc += wc[i].w * mc[i].w * vv.w;
        }
    }

    // ---- P6: 64-lane reduce -> 1 partial per wave ----
    acc += __shfl_down(acc, 32);
    acc += __shfl_down(acc, 16);
    acc += __shfl_down(acc, 8);
    acc += __shfl_down(acc, 4);
    acc += __shfl_down(acc, 2);
    acc += __shfl_down(acc, 1);
    if (lane == 0) wsum[w] = acc;
    asm volatile("s_waitcnt lgkmcnt(0)" ::: "memory");
    SB0();
    __builtin_amdgcn_s_barrier();        // #2: wsum ready; v consumed

    // ---- P7: combine 2 partials + bias, publish (threads 0..7) ----
    if (t < RPB) {
        float s = wsum[2 * t] + wsum[2 * t + 1] + bias;
        float o = (l == N_LAYERS - 1) ? s : s / (1.0f + expf(-s));
        int tb = myidx + WIDTH;
        publish(vals + tb, o, E);
        if (tb >= NUM_NEURONS - WIDTH)
            __hip_atomic_store(out + (tb - (NUM_NEURONS - WIDTH)), o,
                               __ATOMIC_RELAXED, __HIP_MEMORY_SCOPE_AGENT);
    }
    SB0();

    // rotate register-carried scalars
    I_cur = I_next;
    myidx = myidx_nxt;
    bias  = bias_nxt;
}

__global__ __launch_bounds__(NT, 4) void mlp_flow(
    const float* __restrict__ x,
    const float* __restrict__ W,
    const float* __restrict__ M,
    const float* __restrict__ B,
    const int*   __restrict__ IDX,
    u64* __restrict__ vals,          // [NUM_NEURONS] (tag,value)
    u64* __restrict__ ctrl,          // epoch ctrl block, or nullptr (legacy)
    float* __restrict__ out)
{
    __shared__ float v_lds[WIDTH];   // 8KB
    __shared__ float wsum[16];

    const int t    = threadIdx.x;
    const int w    = t >> 6;          // wave 0..15
    const int lane = t & 63;
    const int r    = w >> 1;          // row-in-block 0..7
    const int h    = w & 1;           // K-half 0/1
    const int bid  = blockIdx.x;
    const size_t block_off = (size_t)bid * RPB * WIDTH;
    // per-thread element offset of this wave's slice start within a layer
    const size_t slice_off = block_off + (size_t)r * WIDTH + h * HC + lane * 4;

    // ---- epoch: E = launch index + 1, from persistent done-counter ----
    unsigned E = 1u;
    if (ctrl) {
        u64 d = __hip_atomic_load(&ctrl[1], __ATOMIC_RELAXED,
                                  __HIP_MEMORY_SCOPE_AGENT);
        E = (unsigned)(d >> 8) + 1u;   // done == 256 * launches_completed
    }

    // ---- prologue: zero out slice; once performed, publish input slice ----
    if (t < RPB)
        __hip_atomic_store(out + bid * RPB + t, 0.0f, __ATOMIC_RELAXED,
                           __HIP_MEMORY_SCOPE_AGENT);
    asm volatile("s_waitcnt vmcnt(0)" ::: "memory");
    if (t < RPB) {
        int g = bid * RPB + t;
        publish(vals + g, x[g], E);
    }

    // ---- register-carried per-layer scalars for layer 0 ----
    int2  I_cur   = ((const int2*)IDX)[t];
    int   myidx   = (t < RPB) ? IDX[bid * RPB + t] : 0;
    float bias    = (t < RPB) ? B[bid * RPB + t]   : 0.0f;

    // ---- double-buffered register slices ----
    float4 wA[4], mA[4], wB[4], mB[4];

    // ---- stage layer 0 into A (issue only; resolve of l=0 will wait) ----
    SB0();
    {
        const float* ws = W + slice_off;
        const float* ms = M + slice_off;
#pragma unroll
        for (int i = 0; i < 4; ++i) {
            wA[i] = *(const float4*)(ws + i * 256);
            mA[i] = *(const float4*)(ms + i * 256);
        }
    }
    SB0();

    // ---- main loop, unrolled x2 for static A/B buffer naming ----
    for (int l = 0; l < N_LAYERS; l += 2) {
        layer_body(l,     E, W, M, B, IDX, vals, out,
                   wA, mA, wB, mB, I_cur, myidx, bias,
                   v_lds, wsum, t, w, lane, h, bid, slice_off);
        layer_body(l + 1, E, W, M, B, IDX, vals, out,
                   wB, mB, wA, mA, I_cur, myidx, bias,
                   v_lds, wsum, t, w, lane, h, bid, slice_off);
    }

    // ---- epilogue: advance epoch for the next launch (1 add per block) ----
    if (ctrl && t == 0)
        __hip_atomic_fetch_add(&ctrl[1], 1ull, __ATOMIC_RELAXED,
                               __HIP_MEMORY_SCOPE_AGENT);
}

// ---------- fallback (tiny d_ws): round-1 multi-kernel path, proven ----------
__global__ void init_values(const float* __restrict__ x, float* __restrict__ values) {
    int i = blockIdx.x * blockDim.x + threadIdx.x;
    if (i < NUM_NEURONS) values[i] = (i < WIDTH) ? x[i] : 0.0f;
}
template <bool LAST>
__global__ __launch_bounds__(256) void layer_kernel(
    const float* __restrict__ W, const float* __restrict__ M,
    const float* __restrict__ B, const int* __restrict__ idx,
    float* __restrict__ values)
{
    __shared__ float v_lds[WIDTH];
    __shared__ float ws2[4];
    const int t = threadIdx.x, row = blockIdx.x;
    {
        const int4* idx4 = (const int4*)idx;
        int4 ia = idx4[2 * t], ib = idx4[2 * t + 1];
        float4 va, vb;
        va.x = values[ia.x]; va.y = values[ia.y]; va.z = values[ia.z]; va.w = values[ia.w];
        vb.x = values[ib.x]; vb.y = values[ib.y]; vb.z = values[ib.z]; vb.w = values[ib.w];
        ((float4*)v_lds)[2 * t] = va;
        ((float4*)v_lds)[2 * t + 1] = vb;
    }
    __syncthreads();
    const float4* Wr = (const float4*)(W + (size_t)row * WIDTH);
    const float4* Mr = (const float4*)(M + (size_t)row * WIDTH);
    const float4* Vr = (const float4*)v_lds;
    float acc = 0.0f;
#pragma unroll
    for (int k = 0; k < 2; ++k) {
        int c = t + k * 256;
        float4 w = Wr[c], m = Mr[c], v = Vr[c];
        acc += w.x * m.x * v.x; acc += w.y * m.y * v.y;
        acc += w.z * m.z * v.z; acc += w.w * m.w * v.w;
    }
    acc += __shfl_down(acc, 32); acc += __shfl_down(acc, 16);
    acc += __shfl_down(acc, 8);  acc += __shfl_down(acc, 4);
    acc += __shfl_down(acc, 2);  acc += __shfl_down(acc, 1);
    if ((t & 63) == 0) ws2[t >> 6] = acc;
    __syncthreads();
    if (t == 0) {
        float s = ws2[0] + ws2[1] + ws2[2] + ws2[3] + B[row];
        values[idx[row] + WIDTH] = LAST ? s : s / (1.0f + expf(-s));
    }
}
__global__ void copy_out(const float* __restrict__ src, float* __restrict__ dst) {
    int i = blockIdx.x * blockDim.x + threadIdx.x;
    if (i < WIDTH) dst[i] = src[i];
}

extern "C" void kernel_launch(void* const* d_in, const int* in_sizes, int n_in,
                              void* d_out, int out_size, void* d_ws, size_t ws_size,
                              hipStream_t stream) {
    const float* x   = (const float*)d_in[0];
    const float* W   = (const float*)d_in[1];
    const float* M   = (const float*)d_in[2];
    const float* B   = (const float*)d_in[3];
    const int*   IDX = (const int*)d_in[4];
    float* out = (float*)d_out;

    if (ws_size >= WS_EPOCH_NEEDED) {
        // epoch-tagged dataflow: NO per-launch memset. prep early-outs after
        // the first launch; stream ordering makes its init visible.
        u64* vals = (u64*)d_ws;
        prep<<<64, 256, 0, stream>>>(vals);
        mlp_flow<<<NB, NT, 0, stream>>>(x, W, M, B, IDX, vals,
                                        vals + NUM_NEURONS, out);
    } else if (ws_size >= WS_NEEDED) {
        // legacy path: memset gives tag==0 everywhere; E=1 matches old protocol
        u64* vals = (u64*)d_ws;
        hipMemsetAsync(vals, 0, WS_NEEDED, stream);
        mlp_flow<<<NB, NT, 0, stream>>>(x, W, M, B, IDX, vals, nullptr, out);
    } else {
        float* values = (float*)d_ws;
        init_values<<<(NUM_NEURONS + 255) / 256, 256, 0, stream>>>(x, values);
        for (int l = 0; l < N_LAYERS; ++l) {
            const float* Wl = W + (size_t)l * LAYER_ELEMS;
            const float* Ml = M + (size_t)l * LAYER_ELEMS;
            const float* Bl = B + (size_t)l * WIDTH;
            const int*   Il = IDX + (size_t)l * WIDTH;
            if (l < N_LAYERS - 1)
                layer_kernel<false><<<WIDTH, 256, 0, stream>>>(Wl, Ml, Bl, Il, values);
            else
                layer_kernel<true><<<WIDTH, 256, 0, stream>>>(Wl, Ml, Bl, Il, values);
        }
        copy_out<<<(WIDTH + 255) / 256, 256, 0, stream>>>(values + NUM_NEURONS - WIDTH, out);
    }
}